// Round 18
// baseline (202.625 us; speedup 1.0000x reference)
//
#include <hip/hip_runtime.h>
#include <hip/hip_bf16.h>

typedef short s16;
typedef __attribute__((ext_vector_type(8))) short bf16x8;  // 8 bf16 = 4 VGPR (MFMA A/B frag)
typedef __attribute__((ext_vector_type(4))) float f32x4;   // MFMA C/D frag

// ---------------- helpers ----------------
__device__ __forceinline__ s16 f2bf(float f) {
  unsigned u = __builtin_bit_cast(unsigned, f);
  unsigned r = (u + 0x7FFFu + ((u >> 16) & 1u)) >> 16;
  return (s16)r;
}

__device__ __forceinline__ float hsig(float x) {
  return fminf(fmaxf(0.2f * x + 0.5f, 0.0f), 1.0f);
}

#define PXS 66
#define ROWSZ (PXS * 64)             // 4224 elements per tile row
#define ASZ4 (4 * ROWSZ)             // 4-row tile
#define ASZ6 (6 * ROWSZ)             // 6-row tile (25344 elems)

// ---------------- prep kernel ----------------
// Weight layout per half-tap stage slice (16 KB = 8192 elems):
//   wq[stage u = tap*2+k][j][g][lane][8]
// lane = l4*16+l15, oc = j*64+g*16+l15, ic = k*32+l4*8+e.
__global__ void wprep_kernel(const float* __restrict__ rk0, const float* __restrict__ k1,
                             const float* __restrict__ rk1, const float* __restrict__ k0,
                             s16* __restrict__ w0q, s16* __restrict__ w1q,
                             s16* __restrict__ w2q, s16* __restrict__ k0t) {
  int idx = blockIdx.x * 256 + threadIdx.x;
  const int n1 = 18 * 8192;  // 147456
  if (idx < 3 * n1) {
    int which = idx / n1;
    int i = idx - which * n1;
    int e    = i & 7;
    int lane = (i >> 3) & 63;
    int g    = (i >> 9) & 3;
    int j    = (i >> 11) & 3;
    int k    = (i >> 13) & 1;
    int tap  = i >> 14;
    int l15 = lane & 15, l4 = lane >> 4;
    int ic = k * 32 + l4 * 8 + e;
    int oc = j * 64 + g * 16 + l15;
    const float* src = (which == 0) ? rk0 : (which == 1) ? k1 : rk1;
    s16* dst = (which == 0) ? w0q : (which == 1) ? w1q : w2q;
    dst[i] = f2bf(src[(tap * 64 + ic) * 256 + oc]);
  } else if (idx < 3 * n1 + 8192) {
    int r = idx - 3 * n1;
    int kk = r & 31;
    int oc = r >> 5;
    k0t[r] = (kk < 9) ? f2bf(k0[kk * 256 + oc]) : (s16)0;
  }
}

// ---------------- staging ----------------
template <bool F32>
__device__ __forceinline__ bf16x8 load_conv8(const void* src, long off) {
  if constexpr (F32) {
    const float* p = (const float*)src + off;
    float4 v0 = *reinterpret_cast<const float4*>(p);
    float4 v1 = *reinterpret_cast<const float4*>(p + 4);
    bf16x8 r;
    r[0] = f2bf(v0.x); r[1] = f2bf(v0.y); r[2] = f2bf(v0.z); r[3] = f2bf(v0.w);
    r[4] = f2bf(v1.x); r[5] = f2bf(v1.y); r[6] = f2bf(v1.z); r[7] = f2bf(v1.w);
    return r;
  } else {
    return *reinterpret_cast<const bf16x8*>((const s16*)src + off);
  }
}

// ROWS-row tile staged by NT threads
template <bool F32, int ROWS, int NT>
__device__ __forceinline__ void stageA(s16* a_lds, const void* src, int b, int y0, int tid) {
  #pragma unroll
  for (int i = 0; i < ROWS * 512 / NT; ++i) {
    int c   = tid + i * NT;         // 16B-chunks
    int row = c >> 9;
    int px  = (c >> 3) & 63;
    int cb  = c & 7;
    int y   = y0 - 1 + row;
    int xp  = px + 1;
    bf16x8 v = {};
    if ((unsigned)y < 64u)
      v = load_conv8<F32>(src, ((long)(b * 64 + y) * 64 + px) * 64 + cb * 8);
    *reinterpret_cast<bf16x8*>(a_lds + (row * PXS + xp) * 64 + ((cb ^ (xp & 7)) * 8)) = v;
  }
  if (tid < ROWS * 16) {  // zero x-border columns (xp = 0, 65)
    int row = tid >> 4;
    int xp  = ((tid >> 3) & 1) ? 65 : 0;
    int cb  = tid & 7;
    bf16x8 z = {};
    *reinterpret_cast<bf16x8*>(a_lds + (row * PXS + xp) * 64 + cb * 8) = z;
  }
}

// ---------------- LAYER 0 cell (R17 structure, unchanged: control) ----------------
__global__ __launch_bounds__(1024, 4) void cell0_kernel(
    const float* __restrict__ h0,   // fp32
    const s16* __restrict__ w0,     // wq [18][8192]
    const float* __restrict__ xin,
    const s16* __restrict__ k0t,
    const float* __restrict__ bias,
    const float* __restrict__ c_old,
    float* __restrict__ h_out,
    float* __restrict__ c_out,
    s16* __restrict__ hb_out)
{
  __shared__ __align__(16) s16 a_lds[ASZ4];
  __shared__ __align__(16) s16 w_lds[4][8192];
  __shared__ float x_lds[256];

  const int tid = threadIdx.x;
  const int b  = blockIdx.x >> 5;
  const int y0 = (blockIdx.x & 31) << 1;

  const int wave = tid >> 6;
  const int lane = tid & 63;
  const int g    = wave & 3;
  const int mq   = wave >> 2;
  const int l15  = lane & 15;
  const int l4   = lane >> 4;

  constexpr int NST = 18;

  auto issueW = [&](int u) {
    int v = (u >= NST) ? u - NST : u;
    const s16* wt = w0 + v * 8192;
    char* base = (char*)(&w_lds[0][0]) + (u & 3) * 16384 + (tid >> 6) * 1024;
    __builtin_amdgcn_global_load_lds(
        (const __attribute__((address_space(1))) void*)(wt + tid * 8),
        (__attribute__((address_space(3))) void*)base, 16, 0, 0);
  };
  auto readWf = [&](bf16x8 (&wf)[4], int u) {
    const s16* wb = &w_lds[u & 3][0] + g * 512 + lane * 8;
    #pragma unroll
    for (int j = 0; j < 4; ++j)
      wf[j] = *reinterpret_cast<const bf16x8*>(wb + j * 2048);
  };
  auto readA = [&](bf16x8 (&af)[2], int u) {
    int v = (u >= NST) ? u - NST : u;
    int tap = v >> 1, kk = v & 1;
    int dy = tap / 3, dx = tap - dy * 3;
    const char* sb = (const char*)a_lds + ((mq >> 1) + dy) * (ROWSZ * 2);
    #pragma unroll
    for (int m = 0; m < 2; ++m) {
      int xq   = (mq & 1) * 32 + m * 16 + l15 + dx;
      int boff = xq * 128 + ((((kk << 2) | l4) ^ (xq & 7)) << 4);
      af[m] = *reinterpret_cast<const bf16x8*>(sb + boff);
    }
  };

  f32x4 acc[2][4] = {};

  auto doMfma = [&](const bf16x8 (&af)[2], const bf16x8 (&wf)[4]) {
    __builtin_amdgcn_s_setprio(1);
    #pragma unroll
    for (int m = 0; m < 2; ++m) {
      #pragma unroll
      for (int j = 0; j < 4; ++j)
        acc[m][j] = __builtin_amdgcn_mfma_f32_16x16x32_bf16(af[m], wf[j], acc[m][j], 0, 0, 0);
    }
    __builtin_amdgcn_s_setprio(0);
  };

  issueW(0);
  issueW(1);
  issueW(2);
  stageA<true, 4, 1024>(a_lds, h0, b, y0, tid);
  if (tid < 256) {
    int row = tid >> 6, px = tid & 63;
    int y = y0 - 1 + row;
    x_lds[tid] = ((unsigned)y < 64u) ? xin[(b * 64 + y) * 64 + px] : 0.0f;
  }
  __syncthreads();

  {
    const int rb = mq >> 1;
    #pragma unroll
    for (int m = 0; m < 2; ++m) {
      int px = (mq & 1) * 32 + m * 16 + l15;
      bf16x8 ax = {};
      #pragma unroll
      for (int e = 0; e < 8; ++e) {
        int t = l4 * 8 + e;
        if (t < 9) {
          int dyt = t / 3, dxt = t - dyt * 3;
          int xx = px + dxt - 1;
          float xv = ((unsigned)xx < 64u) ? x_lds[(rb + dyt) * 64 + xx] : 0.0f;
          ax[e] = f2bf(xv);
        }
      }
      #pragma unroll
      for (int j = 0; j < 4; ++j) {
        int oc = j * 64 + g * 16 + l15;
        bf16x8 bx = *reinterpret_cast<const bf16x8*>(k0t + oc * 32 + l4 * 8);
        acc[m][j] = __builtin_amdgcn_mfma_f32_16x16x32_bf16(ax, bx, acc[m][j], 0, 0, 0);
      }
    }
  }

  bf16x8 afA[2], afB[2], wfA[4], wfB[4];
  readA(afA, 0);
  readWf(wfA, 0);
  #pragma unroll
  for (int u = 0; u < NST; u += 2) {
    asm volatile("s_waitcnt vmcnt(1)" ::: "memory");
    __builtin_amdgcn_s_barrier();
    issueW(u + 3);
    readA(afB, u + 1);
    readWf(wfB, u + 1);
    doMfma(afA, wfA);
    asm volatile("s_waitcnt vmcnt(1)" ::: "memory");
    __builtin_amdgcn_s_barrier();
    issueW(u + 4);
    readA(afA, u + 2);
    readWf(wfA, u + 2);
    doMfma(afB, wfB);
  }

  float bi[4];
  #pragma unroll
  for (int j = 0; j < 4; ++j) bi[j] = bias[j * 64 + g * 16 + l15];
  const int pix_base = b * 4096 + y0 * 64;
  const int f = g * 16 + l15;
  #pragma unroll
  for (int m = 0; m < 2; ++m) {
    #pragma unroll
    for (int r = 0; r < 4; ++r) {
      int pl = mq * 32 + m * 16 + l4 * 4 + r;
      int off = (pix_base + pl) * 64 + f;
      float zi = acc[m][0][r] + bi[0];
      float zf = acc[m][1][r] + bi[1];
      float zc = acc[m][2][r] + bi[2];
      float zo = acc[m][3][r] + bi[3];
      float ig = hsig(zi), fg = hsig(zf), og = hsig(zo);
      float cn = fg * c_old[off] + ig * tanhf(zc);
      float hn = og * tanhf(cn);
      c_out[off] = cn;
      h_out[off] = hn;
      hb_out[off] = f2bf(hn);
    }
  }
}

// ---------------- LAYER 1 cell: m_w=8 register tile + R17 schedule ----------------
// Block: 512 threads = 8 waves, 1 block/CU (LDS 147 KB), 2 waves/SIMD.
// Tile: BM=256 px (4 output rows), N=256. Wave (mh = wave>>2 in 0..1 : 128-px
// half, g = wave&3 : oc quarter): acc[8][4] f32x4 = 128 AGPR. Per stage per
// wave: 8 A ds_read + 4 W ds_read feed 32 MFMAs -> 384 B/MFMA (vs R17's 768+).
// W: 3-slot 16 KB ring, issue distance 2, vmcnt(0)-BEFORE-barrier (the drained
// load was issued a full stage earlier, so the wait is ~free), single barrier
// per stage, W-frags register-prefetched one stage ahead (ping-pong), A-frags
// read inline (compiler's fine-grained lgkmcnt pipelines them under the MFMAs).
// grid: 512 blocks: b = blk>>4, y0 = (blk&15)*4.
__global__ __launch_bounds__(512, 2) void cell1_kernel(
    const s16* __restrict__ src0,   // h0nb bf16
    const float* __restrict__ src1, // h1 fp32
    const s16* __restrict__ w0,     // k1 wq
    const s16* __restrict__ w1,     // rk1 wq
    const float* __restrict__ bias,
    const float* __restrict__ c_old,
    float* __restrict__ h_out,
    float* __restrict__ c_out)
{
  __shared__ __align__(16) s16 a_lds[2 * ASZ6];   // 99 KB
  __shared__ __align__(16) s16 w_lds[3][8192];    // 48 KB

  const int tid = threadIdx.x;
  const int b  = blockIdx.x >> 4;
  const int y0 = (blockIdx.x & 15) << 2;

  const int wave = tid >> 6;
  const int lane = tid & 63;
  const int g    = wave & 3;
  const int mh   = wave >> 2;   // 0..1: 128-px half (2 rows)
  const int l15  = lane & 15;
  const int l4   = lane >> 4;

  constexpr int NST = 36;

  // W slice issue: 2 x 16B global_load_lds per thread (16 KB / 512 threads)
  auto issueW = [&](int u) {
    int v = (u >= NST) ? u - NST : u;       // wrap dummy (slot from unwrapped u)
    int si = (v >= 18) ? 1 : 0;
    const s16* wt = (si ? w1 : w0) + (v - 18 * si) * 8192;
    char* sl = (char*)(&w_lds[0][0]) + (u % 3) * 16384 + wave * 1024;
    __builtin_amdgcn_global_load_lds(
        (const __attribute__((address_space(1))) void*)(wt + wave * 512 + lane * 8),
        (__attribute__((address_space(3))) void*)sl, 16, 0, 0);
    __builtin_amdgcn_global_load_lds(
        (const __attribute__((address_space(1))) void*)(wt + 4096 + wave * 512 + lane * 8),
        (__attribute__((address_space(3))) void*)(sl + 8192), 16, 0, 0);
  };

  auto readWf = [&](bf16x8 (&wf)[4], int u) {   // frags of slice u (slot u%3)
    const s16* wb = &w_lds[0][0] + (u % 3) * 8192 + g * 512 + lane * 8;
    #pragma unroll
    for (int j = 0; j < 4; ++j)
      wf[j] = *reinterpret_cast<const bf16x8*>(wb + j * 2048);
  };

  f32x4 acc[8][4] = {};  // 128 AGPR

  auto doStage = [&](const bf16x8 (&wf)[4], int u) {  // u compile-time via unroll
    int si = (u >= 18) ? 1 : 0;
    int uu = u - 18 * si;
    int tap = uu >> 1, kk = uu & 1;
    int dy = tap / 3, dx = tap - dy * 3;
    const char* sb = (const char*)a_lds + si * (ASZ6 * 2);
    bf16x8 af[8];
    #pragma unroll
    for (int m = 0; m < 8; ++m) {
      int row  = 2 * mh + (m >> 2) + dy;   // 0..5
      int xq   = (m & 3) * 16 + l15 + dx;
      int boff = xq * 128 + ((((kk << 2) | l4) ^ (xq & 7)) << 4);
      af[m] = *reinterpret_cast<const bf16x8*>(sb + row * (ROWSZ * 2) + boff);
    }
    __builtin_amdgcn_s_setprio(1);
    #pragma unroll
    for (int m = 0; m < 8; ++m) {
      #pragma unroll
      for (int j = 0; j < 4; ++j)
        acc[m][j] = __builtin_amdgcn_mfma_f32_16x16x32_bf16(af[m], wf[j], acc[m][j], 0, 0, 0);
    }
    __builtin_amdgcn_s_setprio(0);
  };

  // prologue: issue W slices 0,1; stage both A sources
  issueW(0);
  issueW(1);
  stageA<false, 6, 512>(a_lds, src0, b, y0, tid);
  stageA<true, 6, 512>(a_lds + ASZ6, src1, b, y0, tid);
  __syncthreads();   // drains: A staged, W slices 0,1 landed

  bf16x8 wfA[4], wfB[4];
  readWf(wfA, 0);
  #pragma unroll
  for (int u = 0; u < NST; u += 2) {
    // stage u
    asm volatile("s_waitcnt vmcnt(0)" ::: "memory");  // slice u+1 landed (issued @u-1)
    __builtin_amdgcn_s_barrier();                     // all waves' portions landed
    issueW(u + 2);                                    // slot (u+2)%3: readers done @u-2
    readWf(wfB, u + 1);                               // prefetch next frags (overlaps MFMA)
    doStage(wfA, u);
    // stage u+1
    asm volatile("s_waitcnt vmcnt(0)" ::: "memory");  // slice u+2 landed
    __builtin_amdgcn_s_barrier();
    issueW(u + 3);
    readWf(wfA, (u + 2 < NST) ? u + 2 : 0);           // wrap-read unused
    doStage(wfB, u + 1);
  }

  // epilogue
  float bi[4];
  #pragma unroll
  for (int j = 0; j < 4; ++j) bi[j] = bias[j * 64 + g * 16 + l15];
  const int pix_base = b * 4096 + y0 * 64;
  const int f = g * 16 + l15;
  #pragma unroll
  for (int m = 0; m < 8; ++m) {
    #pragma unroll
    for (int r = 0; r < 4; ++r) {
      int pl = (2 * mh + (m >> 2)) * 64 + (m & 3) * 16 + l4 * 4 + r;
      int off = (pix_base + pl) * 64 + f;
      float zi = acc[m][0][r] + bi[0];
      float zf = acc[m][1][r] + bi[1];
      float zc = acc[m][2][r] + bi[2];
      float zo = acc[m][3][r] + bi[3];
      float ig = hsig(zi), fg = hsig(zf), og = hsig(zo);
      float cn = fg * c_old[off] + ig * tanhf(zc);
      float hn = og * tanhf(cn);
      c_out[off] = cn;
      h_out[off] = hn;
    }
  }
}

// ---------------- 1x1 conv head ----------------
__global__ void frames_kernel(const float* __restrict__ h, const float* __restrict__ cw,
                              const float* __restrict__ cbp, float* __restrict__ out) {
  int tid = blockIdx.x * 256 + threadIdx.x;
  int p  = tid >> 2;
  int fc = (tid & 3) * 16;
  const float4* hp = reinterpret_cast<const float4*>(h + p * 64 + fc);
  const float4* wp = reinterpret_cast<const float4*>(cw + fc);
  float s = 0.0f;
  #pragma unroll
  for (int i = 0; i < 4; ++i) {
    float4 v = hp[i];
    float4 w = wp[i];
    s += v.x * w.x + v.y * w.y + v.z * w.z + v.w * w.w;
  }
  s += __shfl_xor(s, 1);
  s += __shfl_xor(s, 2);
  if ((tid & 3) == 0) out[p] = s + cbp[0];
}

// ---------------- launch ----------------
extern "C" void kernel_launch(void* const* d_in, const int* in_sizes, int n_in,
                              void* d_out, int out_size, void* d_ws, size_t ws_size,
                              hipStream_t stream) {
  const float* x   = (const float*)d_in[0];
  const float* h0  = (const float*)d_in[1];
  const float* c0  = (const float*)d_in[2];
  const float* h1  = (const float*)d_in[3];
  const float* c1  = (const float*)d_in[4];
  const float* k0  = (const float*)d_in[5];
  const float* rk0 = (const float*)d_in[6];
  const float* b0  = (const float*)d_in[7];
  const float* k1  = (const float*)d_in[8];
  const float* rk1 = (const float*)d_in[9];
  const float* b1  = (const float*)d_in[10];
  const float* cw  = (const float*)d_in[11];
  const float* cbp = (const float*)d_in[12];

  float* out    = (float*)d_out;
  float* frames = out;                       // [32,64,64,1]
  float* h0n    = out + 131072;              // [32,64,64,64]
  float* c0n    = out + 131072 + 8388608;
  float* h1n    = out + 131072 + 2 * 8388608;
  float* c1n    = out + 131072 + 3 * 8388608;

  char* ws = (char*)d_ws;
  const size_t SZ_H = 16777216;  // bytes per bf16 [32,64,64,64] buffer
  s16* h0nb = (s16*)(ws + 0 * SZ_H);
  s16* w0q  = (s16*)(ws + 1 * SZ_H);                 // rk0 shuffled
  s16* w1q  = (s16*)(ws + 1 * SZ_H + 1 * 294912);    // k1 shuffled
  s16* w2q  = (s16*)(ws + 1 * SZ_H + 2 * 294912);    // rk1 shuffled
  s16* k0t  = (s16*)(ws + 1 * SZ_H + 3 * 294912);    // k0 padded [256][32]

  // prep (single launch)
  wprep_kernel<<<1760, 256, 0, stream>>>(rk0, k1, rk1, k0, w0q, w1q, w2q, k0t);

  // layer 0 (R17 structure, control)
  cell0_kernel<<<1024, 1024, 0, stream>>>(
      h0, w0q, x, k0t, b0, c0, h0n, c0n, h0nb);

  // layer 1 (new m_w=8 structure)
  cell1_kernel<<<512, 512, 0, stream>>>(
      h0nb, h1, w1q, w2q, b1, c1, h1n, c1n);

  // head
  frames_kernel<<<2048, 256, 0, stream>>>(h1n, cw, cbp, frames);
}

// Round 19
// 182.224 us; speedup vs baseline: 1.1120x; 1.1120x over previous
//
#include <hip/hip_runtime.h>
#include <hip/hip_bf16.h>

typedef short s16;
typedef __attribute__((ext_vector_type(8))) short bf16x8;  // 8 bf16 = 4 VGPR (MFMA A/B frag)
typedef __attribute__((ext_vector_type(4))) float f32x4;   // MFMA C/D frag

// ---------------- helpers ----------------
__device__ __forceinline__ s16 f2bf(float f) {
  unsigned u = __builtin_bit_cast(unsigned, f);
  unsigned r = (u + 0x7FFFu + ((u >> 16) & 1u)) >> 16;
  return (s16)r;
}

__device__ __forceinline__ float hsig(float x) {
  return fminf(fmaxf(0.2f * x + 0.5f, 0.0f), 1.0f);
}

#define PXS 66
#define ROWSZ (PXS * 64)             // 4224 elements per tile row
#define ASZ4 (4 * ROWSZ)             // 4-row tile
#define ASZ6 (6 * ROWSZ)             // 6-row tile

// ---------------- prep kernel ----------------
// Weight layout per half-tap stage slice (16 KB = 8192 elems):
//   wq[stage u = tap*2+k][j][g][lane][8]
// lane = l4*16+l15, oc = j*64+g*16+l15, ic = k*32+l4*8+e.
__global__ void wprep_kernel(const float* __restrict__ rk0, const float* __restrict__ k1,
                             const float* __restrict__ rk1, const float* __restrict__ k0,
                             s16* __restrict__ w0q, s16* __restrict__ w1q,
                             s16* __restrict__ w2q, s16* __restrict__ k0t) {
  int idx = blockIdx.x * 256 + threadIdx.x;
  const int n1 = 18 * 8192;  // 147456
  if (idx < 3 * n1) {
    int which = idx / n1;
    int i = idx - which * n1;
    int e    = i & 7;
    int lane = (i >> 3) & 63;
    int g    = (i >> 9) & 3;
    int j    = (i >> 11) & 3;
    int k    = (i >> 13) & 1;
    int tap  = i >> 14;
    int l15 = lane & 15, l4 = lane >> 4;
    int ic = k * 32 + l4 * 8 + e;
    int oc = j * 64 + g * 16 + l15;
    const float* src = (which == 0) ? rk0 : (which == 1) ? k1 : rk1;
    s16* dst = (which == 0) ? w0q : (which == 1) ? w1q : w2q;
    dst[i] = f2bf(src[(tap * 64 + ic) * 256 + oc]);
  } else if (idx < 3 * n1 + 8192) {
    int r = idx - 3 * n1;
    int kk = r & 31;
    int oc = r >> 5;
    k0t[r] = (kk < 9) ? f2bf(k0[kk * 256 + oc]) : (s16)0;
  }
}

// ---------------- staging ----------------
template <bool F32>
__device__ __forceinline__ bf16x8 load_conv8(const void* src, long off) {
  if constexpr (F32) {
    const float* p = (const float*)src + off;
    float4 v0 = *reinterpret_cast<const float4*>(p);
    float4 v1 = *reinterpret_cast<const float4*>(p + 4);
    bf16x8 r;
    r[0] = f2bf(v0.x); r[1] = f2bf(v0.y); r[2] = f2bf(v0.z); r[3] = f2bf(v0.w);
    r[4] = f2bf(v1.x); r[5] = f2bf(v1.y); r[6] = f2bf(v1.z); r[7] = f2bf(v1.w);
    return r;
  } else {
    return *reinterpret_cast<const bf16x8*>((const s16*)src + off);
  }
}

// ROWS-row tile staged by NT threads
template <bool F32, int ROWS, int NT>
__device__ __forceinline__ void stageA(s16* a_lds, const void* src, int b, int y0, int tid) {
  #pragma unroll
  for (int i = 0; i < ROWS * 512 / NT; ++i) {
    int c   = tid + i * NT;         // 16B-chunks
    int row = c >> 9;
    int px  = (c >> 3) & 63;
    int cb  = c & 7;
    int y   = y0 - 1 + row;
    int xp  = px + 1;
    bf16x8 v = {};
    if ((unsigned)y < 64u)
      v = load_conv8<F32>(src, ((long)(b * 64 + y) * 64 + px) * 64 + cb * 8);
    *reinterpret_cast<bf16x8*>(a_lds + (row * PXS + xp) * 64 + ((cb ^ (xp & 7)) * 8)) = v;
  }
  if (tid < ROWS * 16) {  // zero x-border columns (xp = 0, 65)
    int row = tid >> 4;
    int xp  = ((tid >> 3) & 1) ? 65 : 0;
    int cb  = tid & 7;
    bf16x8 z = {};
    *reinterpret_cast<bf16x8*>(a_lds + (row * PXS + xp) * 64 + cb * 8) = z;
  }
}

// ---------------- LAYER 0 cell (R15 structure verbatim -- its measured best) ----------------
// 1024 thr = 16 waves, M=256 (4 output rows, 6-row tile), 3-slot W ring,
// issue distance 2, ONE barrier/stage, counted vmcnt(1). ~42 us measured (R15).
__global__ __launch_bounds__(1024, 1) void cell0_kernel(
    const float* __restrict__ h0,   // fp32
    const s16* __restrict__ w0,     // wq [18][8192]
    const float* __restrict__ xin,
    const s16* __restrict__ k0t,
    const float* __restrict__ bias,
    const float* __restrict__ c_old,
    float* __restrict__ h_out,
    float* __restrict__ c_out,
    s16* __restrict__ hb_out)
{
  __shared__ __align__(16) s16 a_lds[ASZ6];
  __shared__ __align__(16) s16 w_lds[3][8192];
  __shared__ float x_lds[384];

  const int tid = threadIdx.x;
  const int b  = blockIdx.x >> 4;
  const int y0 = (blockIdx.x & 15) << 2;

  const int wave = tid >> 6;
  const int lane = tid & 63;
  const int g    = wave & 3;
  const int mh   = wave >> 2;   // 0..3: output row
  const int l15  = lane & 15;
  const int l4   = lane >> 4;

  constexpr int NST = 18;

  auto issueW = [&](int u) {
    int v = (u >= NST) ? u - NST : u;
    const s16* wt = w0 + v * 8192;
    char* base = (char*)(&w_lds[0][0]) + (v % 3) * 16384 + (tid >> 6) * 1024;
    __builtin_amdgcn_global_load_lds(
        (const __attribute__((address_space(1))) void*)(wt + tid * 8),
        (__attribute__((address_space(3))) void*)base, 16, 0, 0);
  };
  auto readWf = [&](bf16x8 (&wf)[4], int slot) {
    const s16* wb = &w_lds[slot][0] + g * 512 + lane * 8;
    #pragma unroll
    for (int j = 0; j < 4; ++j)
      wf[j] = *reinterpret_cast<const bf16x8*>(wb + j * 2048);
  };

  f32x4 acc[4][4] = {};

  auto doStage = [&](const bf16x8 (&wf)[4], int u) {
    int tap = u >> 1, kk = u & 1;
    int dy = tap / 3, dx = tap - dy * 3;
    const char* sb = (const char*)a_lds + (mh + dy) * (ROWSZ * 2);
    bf16x8 af[4];
    #pragma unroll
    for (int m = 0; m < 4; ++m) {
      int xq   = m * 16 + l15 + dx;
      int boff = xq * 128 + ((((kk << 2) | l4) ^ (xq & 7)) << 4);
      af[m] = *reinterpret_cast<const bf16x8*>(sb + boff);
    }
    __builtin_amdgcn_s_setprio(1);
    #pragma unroll
    for (int m = 0; m < 4; ++m) {
      #pragma unroll
      for (int j = 0; j < 4; ++j)
        acc[m][j] = __builtin_amdgcn_mfma_f32_16x16x32_bf16(af[m], wf[j], acc[m][j], 0, 0, 0);
    }
    __builtin_amdgcn_s_setprio(0);
  };

  issueW(0);
  issueW(1);
  stageA<true, 6, 1024>(a_lds, h0, b, y0, tid);
  if (tid < 384) {
    int row = tid >> 6, px = tid & 63;
    int y = y0 - 1 + row;
    x_lds[tid] = ((unsigned)y < 64u) ? xin[(b * 64 + y) * 64 + px] : 0.0f;
  }
  __syncthreads();

  // x-conv as one zero-padded K=32 MFMA step
  {
    bf16x8 bx[4];
    #pragma unroll
    for (int j = 0; j < 4; ++j) {
      int oc = j * 64 + g * 16 + l15;
      bx[j] = *reinterpret_cast<const bf16x8*>(k0t + oc * 32 + l4 * 8);
    }
    #pragma unroll
    for (int m = 0; m < 4; ++m) {
      int px = m * 16 + l15;
      bf16x8 ax = {};
      #pragma unroll
      for (int e = 0; e < 8; ++e) {
        int t = l4 * 8 + e;
        if (t < 9) {
          int dyt = t / 3, dxt = t - dyt * 3;
          int xx = px + dxt - 1;
          float xv = ((unsigned)xx < 64u) ? x_lds[(mh + dyt) * 64 + xx] : 0.0f;
          ax[e] = f2bf(xv);
        }
      }
      #pragma unroll
      for (int j = 0; j < 4; ++j)
        acc[m][j] = __builtin_amdgcn_mfma_f32_16x16x32_bf16(ax, bx[j], acc[m][j], 0, 0, 0);
    }
  }

  bf16x8 wf[4];
  #pragma unroll
  for (int u = 0; u < NST; ++u) {
    asm volatile("s_waitcnt vmcnt(1)" ::: "memory");  // slice u landed (issued u-2)
    __builtin_amdgcn_s_barrier();                     // publish slice u; retire slot readers
    __builtin_amdgcn_sched_barrier(0);
    issueW(u + 2);                                    // slot (u+2)%3
    readWf(wf, u % 3);
    doStage(wf, u);
  }

  float bi[4];
  #pragma unroll
  for (int j = 0; j < 4; ++j) bi[j] = bias[j * 64 + g * 16 + l15];
  const int pix_base = b * 4096 + y0 * 64;
  const int f = g * 16 + l15;
  #pragma unroll
  for (int m = 0; m < 4; ++m) {
    #pragma unroll
    for (int r = 0; r < 4; ++r) {
      int pl = mh * 64 + m * 16 + l4 * 4 + r;
      int off = (pix_base + pl) * 64 + f;
      float zi = acc[m][0][r] + bi[0];
      float zf = acc[m][1][r] + bi[1];
      float zc = acc[m][2][r] + bi[2];
      float zo = acc[m][3][r] + bi[3];
      float ig = hsig(zi), fg = hsig(zf), og = hsig(zo);
      float cn = fg * c_old[off] + ig * tanhf(zc);
      float hn = og * tanhf(cn);
      c_out[off] = cn;
      h_out[off] = hn;
      hb_out[off] = f2bf(hn);
    }
  }
}

// ---------------- LAYER 1 cell (R17 structure verbatim -- its measured best) ----------------
// 1024 thr = 16 waves, 4 waves/SIMD, M=128, both sources resident (4-row tiles),
// 4-slot W ring, issue distance 3, counted vmcnt(1), dual A/W register prefetch
// one stage ahead, ONE barrier/stage. ~127-128 us measured (R17).
__global__ __launch_bounds__(1024, 4) void cell1_kernel(
    const s16* __restrict__ src0,   // h0nb bf16
    const float* __restrict__ src1, // h1 fp32
    const s16* __restrict__ w0,     // k1 wq
    const s16* __restrict__ w1,     // rk1 wq
    const float* __restrict__ bias,
    const float* __restrict__ c_old,
    float* __restrict__ h_out,
    float* __restrict__ c_out)
{
  __shared__ __align__(16) s16 a_lds[2 * ASZ4];
  __shared__ __align__(16) s16 w_lds[4][8192];

  const int tid = threadIdx.x;
  const int b  = blockIdx.x >> 5;
  const int y0 = (blockIdx.x & 31) << 1;

  const int wave = tid >> 6;
  const int lane = tid & 63;
  const int g    = wave & 3;
  const int mq   = wave >> 2;   // 0..3: 32-px group (row = mq>>1, xhalf = mq&1)
  const int l15  = lane & 15;
  const int l4   = lane >> 4;

  constexpr int NST = 36;

  auto issueW = [&](int u) {
    int v = (u >= NST) ? u - NST : u;   // wrap dummy
    int si = (v >= 18) ? 1 : 0;
    const s16* wt = (si ? w1 : w0) + (v - 18 * si) * 8192;
    char* base = (char*)(&w_lds[0][0]) + (u & 3) * 16384 + (tid >> 6) * 1024;
    __builtin_amdgcn_global_load_lds(
        (const __attribute__((address_space(1))) void*)(wt + tid * 8),
        (__attribute__((address_space(3))) void*)base, 16, 0, 0);
  };

  auto readWf = [&](bf16x8 (&wf)[4], int u) {       // frags of slice u (slot u&3)
    const s16* wb = &w_lds[u & 3][0] + g * 512 + lane * 8;
    #pragma unroll
    for (int j = 0; j < 4; ++j)
      wf[j] = *reinterpret_cast<const bf16x8*>(wb + j * 2048);
  };

  auto readA = [&](bf16x8 (&af)[2], int u) {        // A frags of stage u
    int v = (u >= NST) ? u - NST : u;               // wrap dummy
    int si = (v >= 18) ? 1 : 0;
    int uu = v - 18 * si;
    int tap = uu >> 1, kk = uu & 1;
    int dy = tap / 3, dx = tap - dy * 3;
    const char* sb = (const char*)a_lds + si * (ASZ4 * 2) + ((mq >> 1) + dy) * (ROWSZ * 2);
    #pragma unroll
    for (int m = 0; m < 2; ++m) {
      int xq   = (mq & 1) * 32 + m * 16 + l15 + dx;
      int boff = xq * 128 + ((((kk << 2) | l4) ^ (xq & 7)) << 4);
      af[m] = *reinterpret_cast<const bf16x8*>(sb + boff);
    }
  };

  f32x4 acc[2][4] = {};  // 32 AGPR

  auto doMfma = [&](const bf16x8 (&af)[2], const bf16x8 (&wf)[4]) {
    __builtin_amdgcn_s_setprio(1);
    #pragma unroll
    for (int m = 0; m < 2; ++m) {
      #pragma unroll
      for (int j = 0; j < 4; ++j)
        acc[m][j] = __builtin_amdgcn_mfma_f32_16x16x32_bf16(af[m], wf[j], acc[m][j], 0, 0, 0);
    }
    __builtin_amdgcn_s_setprio(0);
  };

  issueW(0);
  issueW(1);
  issueW(2);
  stageA<false, 4, 1024>(a_lds, src0, b, y0, tid);
  stageA<true, 4, 1024>(a_lds + ASZ4, src1, b, y0, tid);
  __syncthreads();   // drains all: A staged, W slices 0..2 landed

  bf16x8 afA[2], afB[2], wfA[4], wfB[4];
  readA(afA, 0);
  readWf(wfA, 0);
  #pragma unroll
  for (int u = 0; u < NST; u += 2) {
    asm volatile("s_waitcnt vmcnt(1)" ::: "memory");  // slice u+1 landed
    __builtin_amdgcn_s_barrier();                     // publish; retire slot readers
    issueW(u + 3);                                    // slot (u+3)&3
    readA(afB, u + 1);
    readWf(wfB, u + 1);                               // overlaps doMfma below
    doMfma(afA, wfA);
    asm volatile("s_waitcnt vmcnt(1)" ::: "memory");  // slice u+2 landed
    __builtin_amdgcn_s_barrier();
    issueW(u + 4);
    readA(afA, u + 2);
    readWf(wfA, u + 2);
    doMfma(afB, wfB);
  }

  float bi[4];
  #pragma unroll
  for (int j = 0; j < 4; ++j) bi[j] = bias[j * 64 + g * 16 + l15];
  const int pix_base = b * 4096 + y0 * 64;
  const int f = g * 16 + l15;
  #pragma unroll
  for (int m = 0; m < 2; ++m) {
    #pragma unroll
    for (int r = 0; r < 4; ++r) {
      int pl = mq * 32 + m * 16 + l4 * 4 + r;
      int off = (pix_base + pl) * 64 + f;
      float zi = acc[m][0][r] + bi[0];
      float zf = acc[m][1][r] + bi[1];
      float zc = acc[m][2][r] + bi[2];
      float zo = acc[m][3][r] + bi[3];
      float ig = hsig(zi), fg = hsig(zf), og = hsig(zo);
      float cn = fg * c_old[off] + ig * tanhf(zc);
      float hn = og * tanhf(cn);
      c_out[off] = cn;
      h_out[off] = hn;
    }
  }
}

// ---------------- 1x1 conv head ----------------
__global__ void frames_kernel(const float* __restrict__ h, const float* __restrict__ cw,
                              const float* __restrict__ cbp, float* __restrict__ out) {
  int tid = blockIdx.x * 256 + threadIdx.x;
  int p  = tid >> 2;
  int fc = (tid & 3) * 16;
  const float4* hp = reinterpret_cast<const float4*>(h + p * 64 + fc);
  const float4* wp = reinterpret_cast<const float4*>(cw + fc);
  float s = 0.0f;
  #pragma unroll
  for (int i = 0; i < 4; ++i) {
    float4 v = hp[i];
    float4 w = wp[i];
    s += v.x * w.x + v.y * w.y + v.z * w.z + v.w * w.w;
  }
  s += __shfl_xor(s, 1);
  s += __shfl_xor(s, 2);
  if ((tid & 3) == 0) out[p] = s + cbp[0];
}

// ---------------- launch ----------------
extern "C" void kernel_launch(void* const* d_in, const int* in_sizes, int n_in,
                              void* d_out, int out_size, void* d_ws, size_t ws_size,
                              hipStream_t stream) {
  const float* x   = (const float*)d_in[0];
  const float* h0  = (const float*)d_in[1];
  const float* c0  = (const float*)d_in[2];
  const float* h1  = (const float*)d_in[3];
  const float* c1  = (const float*)d_in[4];
  const float* k0  = (const float*)d_in[5];
  const float* rk0 = (const float*)d_in[6];
  const float* b0  = (const float*)d_in[7];
  const float* k1  = (const float*)d_in[8];
  const float* rk1 = (const float*)d_in[9];
  const float* b1  = (const float*)d_in[10];
  const float* cw  = (const float*)d_in[11];
  const float* cbp = (const float*)d_in[12];

  float* out    = (float*)d_out;
  float* frames = out;                       // [32,64,64,1]
  float* h0n    = out + 131072;              // [32,64,64,64]
  float* c0n    = out + 131072 + 8388608;
  float* h1n    = out + 131072 + 2 * 8388608;
  float* c1n    = out + 131072 + 3 * 8388608;

  char* ws = (char*)d_ws;
  const size_t SZ_H = 16777216;  // bytes per bf16 [32,64,64,64] buffer
  s16* h0nb = (s16*)(ws + 0 * SZ_H);
  s16* w0q  = (s16*)(ws + 1 * SZ_H);                 // rk0 shuffled
  s16* w1q  = (s16*)(ws + 1 * SZ_H + 1 * 294912);    // k1 shuffled
  s16* w2q  = (s16*)(ws + 1 * SZ_H + 2 * 294912);    // rk1 shuffled
  s16* k0t  = (s16*)(ws + 1 * SZ_H + 3 * 294912);    // k0 padded [256][32]

  // prep (single launch)
  wprep_kernel<<<1760, 256, 0, stream>>>(rk0, k1, rk1, k0, w0q, w1q, w2q, k0t);

  // layer 0 (R15 structure: measured best L0, ~42 us)
  cell0_kernel<<<512, 1024, 0, stream>>>(
      h0, w0q, x, k0t, b0, c0, h0n, c0n, h0nb);

  // layer 1 (R17 structure: measured best L1, ~127 us)
  cell1_kernel<<<1024, 1024, 0, stream>>>(
      h0nb, h1, w1q, w2q, b1, c1, h1n, c1n);

  // head
  frames_kernel<<<2048, 256, 0, stream>>>(h1n, cw, cbp, frames);
}